// Round 18
// baseline (67.351 us; speedup 1.0000x reference)
//
#include <hip/hip_runtime.h>

#define NE 8               // experts
#define H4 512             // float4 per token row (2048 floats)
#define NTOK 16384         // 4 * 4096 tokens
#define TPW 4              // tokens per wave (full K per wave)
#define TPB 16             // tokens per block (4 independent waves)
#define NBLK_A (NTOK / TPB)  // 1024 blocks
#define NBLK_B 64          // finish-kernel blocks (16384 / 256)
#define AUX_COEF 0.01f

// ws layout (floats): part[NTOK][NE] = 131072 | ws2[NBLK_B*16]
#define WS2_OFF (NTOK * NE)

typedef float f4v __attribute__((ext_vector_type(4)));

// Kernel A (hot): QK=1 streaming GEMV — each wave does 4 tokens x full
// 2048 cols (R16's proven loop). NEW: fold-reduction replaces the full
// butterfly — 31 shuffles + 1 instead of 192. At step k, lane keeps the
// value-half whose index-bit-k matches its lane-bit-k, receives partner's
// matching half; after 5 steps V[0] = its own (lane&31) value summed over
// the 32-lane group; one xor-32 add completes the 64-lane sum.
__global__ __launch_bounds__(256, 4)
void router_partial(const float* __restrict__ hs, const float* __restrict__ gw,
                    float* __restrict__ part)
{
    const int tid  = threadIdx.x;
    const int wave = tid >> 6, lane = tid & 63;
    const int tok0 = blockIdx.x * TPB + wave * TPW;

    const f4v* __restrict__ hs4 = (const f4v*)hs;
    const f4v* __restrict__ gw4 = (const f4v*)gw;

    float acc[TPW][NE];
    #pragma unroll
    for (int r = 0; r < TPW; ++r)
        #pragma unroll
        for (int e = 0; e < NE; ++e) acc[r][e] = 0.f;

    #pragma unroll
    for (int it = 0; it < 8; ++it) {
        const int col = it * 64 + lane;
        f4v h[TPW];
        #pragma unroll
        for (int r = 0; r < TPW; ++r)
            h[r] = hs4[(size_t)(tok0 + r) * H4 + col];
        f4v g[NE];
        #pragma unroll
        for (int e = 0; e < NE; ++e) g[e] = gw4[e * H4 + col];
        #pragma unroll
        for (int r = 0; r < TPW; ++r)
            #pragma unroll
            for (int e = 0; e < NE; ++e)
                acc[r][e] += h[r].x * g[e].x + h[r].y * g[e].y
                           + h[r].z * g[e].z + h[r].w * g[e].w;
    }

    // V[j] = acc[j>>3][j&7]; value index j: bits 0-2 = expert, bits 3-4 = row
    float V[32];
    #pragma unroll
    for (int j = 0; j < 32; ++j) V[j] = acc[j >> 3][j & 7];

    // fold steps k = 0..4: halve values per lane, summing partner pairs.
    // All array indices are compile-time constants (k, m unrolled).
    #pragma unroll
    for (int k = 0; k < 5; ++k) {
        const int S = 32 >> k;
        const bool hi = (lane >> k) & 1;
        float NV[16];
        #pragma unroll
        for (int m = 0; m < 16; ++m) {
            if (m < S / 2) {
                const float keep = hi ? V[2 * m + 1] : V[2 * m];
                const float send = hi ? V[2 * m]     : V[2 * m + 1];
                const float recv = __shfl_xor(send, 1 << k, 64);
                NV[m] = keep + recv;
            }
        }
        #pragma unroll
        for (int m = 0; m < 16; ++m)
            if (m < S / 2) V[m] = NV[m];
    }
    const float tot = V[0] + __shfl_xor(V[0], 32, 64);

    // lane L (0..31) holds value idx = L&31 -> (token L>>3, expert L&7):
    // one coalesced 128 B store per wave, same layout as R16
    if (lane < 32)
        part[(size_t)(tok0 + (lane >> 3)) * NE + (lane & 7)] = tot;
}

// Kernel B: one thread per token. Read its 8 logits (32 B), softmax +
// top-2 + renorm, coalesced float2 outputs, per-block aux partial.
__global__ __launch_bounds__(256)
void router_finish(const float* __restrict__ part, float* __restrict__ out,
                   float* __restrict__ ws2)
{
    __shared__ float red[4][2 * NE];
    const int tid = threadIdx.x;
    const int t   = blockIdx.x * 256 + tid;      // token
    const float4* __restrict__ p4 = (const float4*)part;

    float lg[NE];
    {
        float4 a = p4[(size_t)t * 2],  b = p4[(size_t)t * 2 + 1];
        lg[0]=a.x; lg[1]=a.y; lg[2]=a.z; lg[3]=a.w;
        lg[4]=b.x; lg[5]=b.y; lg[6]=b.z; lg[7]=b.w;
    }

    float m = lg[0];
    #pragma unroll
    for (int e = 1; e < NE; ++e) m = fmaxf(m, lg[e]);
    float p[NE];
    float s = 0.f;
    #pragma unroll
    for (int e = 0; e < NE; ++e) { p[e] = __expf(lg[e] - m); s += p[e]; }
    const float inv = 1.f / s;

    // top-2 on probs; strict '>' keeps lowest index on ties (lax.top_k order)
    float v0 = -1.f; int i0 = 0;
    #pragma unroll
    for (int e = 0; e < NE; ++e) { if (p[e] > v0) { v0 = p[e]; i0 = e; } }
    float v1 = -1.f; int i1 = 0;
    #pragma unroll
    for (int e = 0; e < NE; ++e) { if (e != i0 && p[e] > v1) { v1 = p[e]; i1 = e; } }

    float2* __restrict__ o2 = (float2*)out;
    const float wsum = v0 + v1;
    o2[t]        = make_float2(v0 / wsum, v1 / wsum);
    o2[NTOK + t] = make_float2((float)i0, (float)i1);

    // aux partials: every thread owns exactly one token
    float qv[NE], c[NE];
    #pragma unroll
    for (int e = 0; e < NE; ++e) {
        qv[e] = p[e] * inv;
        c[e]  = ((i0 == e) ? 1.f : 0.f) + ((i1 == e) ? 1.f : 0.f);
    }
    #pragma unroll
    for (int e = 0; e < NE; ++e) {
        #pragma unroll
        for (int sh = 32; sh > 0; sh >>= 1) {
            qv[e] += __shfl_xor(qv[e], sh, 64);
            c[e]  += __shfl_xor(c[e],  sh, 64);
        }
    }
    const int wave = tid >> 6, lane = tid & 63;
    if (lane == 0) {
        #pragma unroll
        for (int e = 0; e < NE; ++e) {
            red[wave][e]      = qv[e];
            red[wave][NE + e] = c[e];
        }
    }
    __syncthreads();
    if (tid < 2 * NE) {
        float sum = red[0][tid] + red[1][tid] + red[2][tid] + red[3][tid];
        ws2[blockIdx.x * 2 * NE + tid] = sum;
    }
}

// Kernel C: reduce 64 x 16 partials -> aux scalar
__global__ __launch_bounds__(128)
void router_aux2(const float* __restrict__ ws2, float* __restrict__ out)
{
    __shared__ float red[8][16];
    __shared__ float tot[16];
    const int tid = threadIdx.x;
    const int e = tid & 15, row = tid >> 4;      // 8 rows x 16
    float s = 0.f;
    #pragma unroll
    for (int k = 0; k < NBLK_B / 8; ++k)
        s += ws2[(row * (NBLK_B / 8) + k) * 16 + e];
    red[row][e] = s;
    __syncthreads();
    if (tid < 16) {
        float t2 = 0.f;
        #pragma unroll
        for (int r = 0; r < 8; ++r) t2 += red[r][tid];
        tot[tid] = t2;
    }
    __syncthreads();
    if (tid == 0) {
        float s2 = 0.f;
        #pragma unroll
        for (int e2 = 0; e2 < NE; ++e2) {
            const float ef = tot[NE + e2] / (float)(NTOK * 2);  // expert_frac
            const float rf = tot[e2] / (float)NTOK;             // router_frac
            s2 += ef * rf;
        }
        out[4 * NTOK] = (float)NE * s2 * AUX_COEF;
    }
}

extern "C" void kernel_launch(void* const* d_in, const int* in_sizes, int n_in,
                              void* d_out, int out_size, void* d_ws, size_t ws_size,
                              hipStream_t stream)
{
    const float* hs = (const float*)d_in[0];   // [4,4096,2048] f32
    const float* gw = (const float*)d_in[1];   // [8,2048] f32
    float* out  = (float*)d_out;               // 32768 rw | 32768 idx | 1 aux
    float* part = (float*)d_ws;                // [16384][8] logits
    float* ws2  = (float*)d_ws + WS2_OFF;      // [64][16] aux partials

    hipLaunchKernelGGL(router_partial, dim3(NBLK_A), dim3(256), 0,
                       stream, hs, gw, part);
    hipLaunchKernelGGL(router_finish, dim3(NBLK_B), dim3(256), 0,
                       stream, part, out, ws2);
    hipLaunchKernelGGL(router_aux2, dim3(1), dim3(128), 0, stream, ws2, out);
}

// Round 19
// 33.241 us; speedup vs baseline: 2.0262x; 2.0262x over previous
//
#include <hip/hip_runtime.h>

#define NE 8               // experts
#define H4 512             // float4 per token row (2048 floats)
#define NTOK 16384         // 4 * 4096 tokens
#define TPW 4              // tokens per wave (full K per wave)
#define TPB 16             // tokens per block (4 independent waves)
#define NBLK_A (NTOK / TPB)  // 1024 blocks
#define NBLK_B 64          // finish-kernel blocks (16384 / 256)
#define AUX_COEF 0.01f

// ws layout (floats): part[NTOK][NE] = 131072 | ws2[NBLK_B*16]
#define WS2_OFF (NTOK * NE)

typedef float f4v __attribute__((ext_vector_type(4)));

// Kernel A (hot): QK=1 streaming GEMV (R16's proven loop). Reduction is an
// IN-PLACE fold on acc[4][8] — no staging copies (R18's spill bug):
// 32 shuffles total vs 192 for the full butterfly. Phase 1 folds experts
// (xor 1,2,4), phase 2 folds tokens (xor 8,16), final xor-32 add.
// Lane L<32 ends with the full logit of (token (L>>3)&3, expert L&7).
__global__ __launch_bounds__(256, 4)
void router_partial(const float* __restrict__ hs, const float* __restrict__ gw,
                    float* __restrict__ part)
{
    const int tid  = threadIdx.x;
    const int wave = tid >> 6, lane = tid & 63;
    const int tok0 = blockIdx.x * TPB + wave * TPW;

    const f4v* __restrict__ hs4 = (const f4v*)hs;
    const f4v* __restrict__ gw4 = (const f4v*)gw;

    float acc[TPW][NE];
    #pragma unroll
    for (int r = 0; r < TPW; ++r)
        #pragma unroll
        for (int e = 0; e < NE; ++e) acc[r][e] = 0.f;

    #pragma unroll
    for (int it = 0; it < 8; ++it) {
        const int col = it * 64 + lane;
        f4v h[TPW];
        #pragma unroll
        for (int r = 0; r < TPW; ++r)
            h[r] = hs4[(size_t)(tok0 + r) * H4 + col];
        f4v g[NE];
        #pragma unroll
        for (int e = 0; e < NE; ++e) g[e] = gw4[e * H4 + col];
        #pragma unroll
        for (int r = 0; r < TPW; ++r)
            #pragma unroll
            for (int e = 0; e < NE; ++e)
                acc[r][e] += h[r].x * g[e].x + h[r].y * g[e].y
                           + h[r].z * g[e].z + h[r].w * g[e].w;
    }

    // phase 1: fold expert dim in place (steps xor 1, 2, 4)
    #pragma unroll
    for (int r = 0; r < TPW; ++r) {
        {   // xor 1: 8 -> 4
            const bool hi = lane & 1;
            #pragma unroll
            for (int m = 0; m < 4; ++m) {
                const float keep = hi ? acc[r][2*m+1] : acc[r][2*m];
                const float send = hi ? acc[r][2*m]   : acc[r][2*m+1];
                acc[r][m] = keep + __shfl_xor(send, 1, 64);
            }
        }
        {   // xor 2: 4 -> 2
            const bool hi = (lane >> 1) & 1;
            #pragma unroll
            for (int m = 0; m < 2; ++m) {
                const float keep = hi ? acc[r][2*m+1] : acc[r][2*m];
                const float send = hi ? acc[r][2*m]   : acc[r][2*m+1];
                acc[r][m] = keep + __shfl_xor(send, 2, 64);
            }
        }
        {   // xor 4: 2 -> 1
            const bool hi = (lane >> 2) & 1;
            const float keep = hi ? acc[r][1] : acc[r][0];
            const float send = hi ? acc[r][0] : acc[r][1];
            acc[r][0] = keep + __shfl_xor(send, 4, 64);
        }
    }

    // phase 2: fold token dim (xor 8, then xor 16)
    float T0, T1;
    {
        const bool hi = (lane >> 3) & 1;
        const float k0 = hi ? acc[1][0] : acc[0][0];
        const float s0 = hi ? acc[0][0] : acc[1][0];
        T0 = k0 + __shfl_xor(s0, 8, 64);
        const float k1 = hi ? acc[3][0] : acc[2][0];
        const float s1 = hi ? acc[2][0] : acc[3][0];
        T1 = k1 + __shfl_xor(s1, 8, 64);
    }
    float T;
    {
        const bool hi = (lane >> 4) & 1;
        const float k = hi ? T1 : T0;
        const float sd = hi ? T0 : T1;
        T = k + __shfl_xor(sd, 16, 64);
    }
    const float tot = T + __shfl_xor(T, 32, 64);

    // lane L<32 stores (token (L>>3)&3, expert L&7): 128 B coalesced/wave
    if (lane < 32)
        part[(size_t)(tok0 + ((lane >> 3) & 3)) * NE + (lane & 7)] = tot;
}

// Kernel B: one thread per token. Read its 8 logits (32 B), softmax +
// top-2 + renorm, coalesced float2 outputs, per-block aux partial.
__global__ __launch_bounds__(256)
void router_finish(const float* __restrict__ part, float* __restrict__ out,
                   float* __restrict__ ws2)
{
    __shared__ float red[4][2 * NE];
    const int tid = threadIdx.x;
    const int t   = blockIdx.x * 256 + tid;      // token
    const float4* __restrict__ p4 = (const float4*)part;

    float lg[NE];
    {
        float4 a = p4[(size_t)t * 2],  b = p4[(size_t)t * 2 + 1];
        lg[0]=a.x; lg[1]=a.y; lg[2]=a.z; lg[3]=a.w;
        lg[4]=b.x; lg[5]=b.y; lg[6]=b.z; lg[7]=b.w;
    }

    float m = lg[0];
    #pragma unroll
    for (int e = 1; e < NE; ++e) m = fmaxf(m, lg[e]);
    float p[NE];
    float s = 0.f;
    #pragma unroll
    for (int e = 0; e < NE; ++e) { p[e] = __expf(lg[e] - m); s += p[e]; }
    const float inv = 1.f / s;

    // top-2 on probs; strict '>' keeps lowest index on ties (lax.top_k order)
    float v0 = -1.f; int i0 = 0;
    #pragma unroll
    for (int e = 0; e < NE; ++e) { if (p[e] > v0) { v0 = p[e]; i0 = e; } }
    float v1 = -1.f; int i1 = 0;
    #pragma unroll
    for (int e = 0; e < NE; ++e) { if (e != i0 && p[e] > v1) { v1 = p[e]; i1 = e; } }

    float2* __restrict__ o2 = (float2*)out;
    const float wsum = v0 + v1;
    o2[t]        = make_float2(v0 / wsum, v1 / wsum);
    o2[NTOK + t] = make_float2((float)i0, (float)i1);

    // aux partials: every thread owns exactly one token
    float qv[NE], c[NE];
    #pragma unroll
    for (int e = 0; e < NE; ++e) {
        qv[e] = p[e] * inv;
        c[e]  = ((i0 == e) ? 1.f : 0.f) + ((i1 == e) ? 1.f : 0.f);
    }
    #pragma unroll
    for (int e = 0; e < NE; ++e) {
        #pragma unroll
        for (int sh = 32; sh > 0; sh >>= 1) {
            qv[e] += __shfl_xor(qv[e], sh, 64);
            c[e]  += __shfl_xor(c[e],  sh, 64);
        }
    }
    const int wave = tid >> 6, lane = tid & 63;
    if (lane == 0) {
        #pragma unroll
        for (int e = 0; e < NE; ++e) {
            red[wave][e]      = qv[e];
            red[wave][NE + e] = c[e];
        }
    }
    __syncthreads();
    if (tid < 2 * NE) {
        float sum = red[0][tid] + red[1][tid] + red[2][tid] + red[3][tid];
        ws2[blockIdx.x * 2 * NE + tid] = sum;
    }
}

// Kernel C: reduce 64 x 16 partials -> aux scalar
__global__ __launch_bounds__(128)
void router_aux2(const float* __restrict__ ws2, float* __restrict__ out)
{
    __shared__ float red[8][16];
    __shared__ float tot[16];
    const int tid = threadIdx.x;
    const int e = tid & 15, row = tid >> 4;      // 8 rows x 16
    float s = 0.f;
    #pragma unroll
    for (int k = 0; k < NBLK_B / 8; ++k)
        s += ws2[(row * (NBLK_B / 8) + k) * 16 + e];
    red[row][e] = s;
    __syncthreads();
    if (tid < 16) {
        float t2 = 0.f;
        #pragma unroll
        for (int r = 0; r < 8; ++r) t2 += red[r][tid];
        tot[tid] = t2;
    }
    __syncthreads();
    if (tid == 0) {
        float s2 = 0.f;
        #pragma unroll
        for (int e2 = 0; e2 < NE; ++e2) {
            const float ef = tot[NE + e2] / (float)(NTOK * 2);  // expert_frac
            const float rf = tot[e2] / (float)NTOK;             // router_frac
            s2 += ef * rf;
        }
        out[4 * NTOK] = (float)NE * s2 * AUX_COEF;
    }
}

extern "C" void kernel_launch(void* const* d_in, const int* in_sizes, int n_in,
                              void* d_out, int out_size, void* d_ws, size_t ws_size,
                              hipStream_t stream)
{
    const float* hs = (const float*)d_in[0];   // [4,4096,2048] f32
    const float* gw = (const float*)d_in[1];   // [8,2048] f32
    float* out  = (float*)d_out;               // 32768 rw | 32768 idx | 1 aux
    float* part = (float*)d_ws;                // [16384][8] logits
    float* ws2  = (float*)d_ws + WS2_OFF;      // [64][16] aux partials

    hipLaunchKernelGGL(router_partial, dim3(NBLK_A), dim3(256), 0,
                       stream, hs, gw, part);
    hipLaunchKernelGGL(router_finish, dim3(NBLK_B), dim3(256), 0,
                       stream, part, out, ws2);
    hipLaunchKernelGGL(router_aux2, dim3(1), dim3(128), 0, stream, ws2, out);
}